// Round 14
// baseline (155.705 us; speedup 1.0000x reference)
//
#include <hip/hip_runtime.h>

#define DEV_INLINE __device__ __forceinline__

// Problem constants
#define PI_F 3.14159265358979323846f

// ws layout (float offsets)
#define H_OFF     0          // 2048
#define SINO_OFF  2048       // 65536
#define DIFF_OFF  67584      // 65536
#define XIN_OFF   133120     // 65536
#define WF2F_OFF  198656     // 4608 ints (18 groups x 64 lanes x int4)
#define WF1B_OFF  207872     // 4608 ints
#define WF2B_OFF  212480     // 256 ints (B-frag of conv2_backward weights)
#define BUFA_OFF  217088     // quadP lives here (258*258 float4)
#define BUFB_OFF  2314240    // xfp: x_forward as 16 int planes (bf16 pairs)

typedef short bf16x8 __attribute__((ext_vector_type(8)));
typedef float f32x4 __attribute__((ext_vector_type(4)));

union FragI4 { int4 i4; bf16x8 v; };
union FragI  { int i[4]; bf16x8 v; };

DEV_INLINE unsigned rne1(float a) {
  unsigned u = __float_as_uint(a);
  return (u + 0x7FFFu + ((u >> 16) & 1u)) >> 16;
}
DEV_INLINE int pack_rne(float a, float b) {
  return (int)(rne1(a) | (rne1(b) << 16));
}

// ---------------------------------------------------------------------------
// Setup: h | wf2f | wf1b | wf2b | quadP | x_input=x. (diff init removed:
// filt64 writes diff = filtered - sino directly.)
// blocks: 0..63 h | 64..81 wf2f | 82..99 wf1b | 100 wf2b | 101..361 quadP |
//         362..617 x_input=x
// ---------------------------------------------------------------------------
__global__ __launch_bounds__(256) void setup_kernel(
    const float* __restrict__ w2f, const float* __restrict__ w1b,
    const float* __restrict__ w2b, const float* __restrict__ img,
    float* __restrict__ h, int* __restrict__ wf2f, int* __restrict__ wf1b,
    int* __restrict__ wf2b, float4* __restrict__ quadP,
    float* __restrict__ x_input) {
  const int b = blockIdx.x;
  const int tid = threadIdx.x;
  if (b < 64) {
    __shared__ float hp[8][32];
    const int cell = tid & 31;
    const int kq = tid >> 5;
    const int n = b * 32 + cell;
    float ssum = 0.0f;
    const float ang_scale = PI_F / 1024.0f;
    for (int k = kq * 128; k < kq * 128 + 128; ++k) {
      int m = (k * n) & 2047;             // exact angle reduction mod 2*pi
      ssum += (float)k * __cosf((float)m * ang_scale);
    }
    hp[kq][cell] = ssum;
    __syncthreads();
    if (tid < 32) {
      float S = 0.0f;
      #pragma unroll
      for (int q = 0; q < 8; ++q) S += hp[q][tid];
      int nn = b * 32 + tid;
      float sgn = (nn & 1) ? -1.0f : 1.0f;
      h[nn] = (S * (1.0f / 512.0f) + sgn) * (1.0f / 2048.0f);
    }
  } else if (b < 100) {
    const bool second = (b >= 82);
    int idx = (b - (second ? 82 : 64)) * 256 + tid;   // < 4608
    int d = idx & 3;
    int L = (idx >> 2) & 63;
    int jm = idx >> 8;                    // 0..17
    int j = jm >> 1, mt = jm & 1;
    int co = mt * 16 + (L & 15);
    int ci0 = (L >> 4) * 8 + 2 * d;
    const float* w = second ? w1b : w2f;
    int v = pack_rne(w[co * 288 + ci0 * 9 + j], w[co * 288 + (ci0 + 1) * 9 + j]);
    (second ? wf1b : wf2f)[idx] = v;
  } else if (b < 101) {
    // wf2b B-frag: 256 ints; n>=9 columns zero.
    int d = tid & 3;
    int L = tid >> 2;
    int n = L & 15;
    int k0 = (L >> 4) * 8 + 2 * d;
    float lo = (n < 9) ? w2b[k0 * 9 + n] : 0.0f;
    float hi = (n < 9) ? w2b[(k0 + 1) * 9 + n] : 0.0f;
    wf2b[tid] = pack_rne(lo, hi);
  } else if (b < 362) {
    int idx = (b - 101) * 256 + tid;
    if (idx < 258 * 258) {
      int y = idx / 258;
      int x = idx - y * 258;
      float4 v;
      int ay = y - 1, bx = x - 1;          // img coords for P(y,x)
      bool y0ok = (ay >= 0 && ay < 256);
      bool y1ok = (ay + 1 >= 0 && ay + 1 < 256);
      bool x0ok = (bx >= 0 && bx < 256);
      bool x1ok = (bx + 1 >= 0 && bx + 1 < 256);
      v.x = (y0ok && x0ok) ? img[(ay << 8) + bx] : 0.0f;
      v.y = (y0ok && x1ok) ? img[(ay << 8) + bx + 1] : 0.0f;
      v.z = (y1ok && x0ok) ? img[((ay + 1) << 8) + bx] : 0.0f;
      v.w = (y1ok && x1ok) ? img[((ay + 1) << 8) + bx + 1] : 0.0f;
      quadP[idx] = v;
    }
  } else {
    int idx = (b - 362) * 256 + tid;      // < 65536
    x_input[idx] = img[idx];
  }
}

// ---------------------------------------------------------------------------
// Fan-beam forward projection (verified, unchanged).
// ---------------------------------------------------------------------------
__global__ __launch_bounds__(256) void fwdproj(
    const float4* __restrict__ quadP, const float* __restrict__ theta,
    float* __restrict__ sino) {
  __shared__ float part[8][32];
  __shared__ float cs[2];
  const int tid = threadIdx.x;
  const int a = blockIdx.x >> 5;
  const int cell = tid & 31;
  const int chunk = tid >> 5;
  const int d = ((blockIdx.x & 31) << 5) + cell;
  if (tid == 0) {
    float th = theta[a];
    cs[0] = cosf(th);
    cs[1] = sinf(th);
  }
  __syncthreads();
  const float c = cs[0], s = cs[1];
  const float u = ((float)d - 511.5f) * 2.0f;
  const float dxv = -1000.0f * c - u * s;
  const float dyv = -1000.0f * s + u * c;
  const float L = sqrtf(1.0e6f + u * u);
  const float sx = fmaf(500.0f, c, 127.5f);
  const float sy = fmaf(500.0f, s, 127.5f);

  float tlo = 0.0f, thi = 1.0f;
  if (fabsf(dxv) > 1e-6f) {
    float inv = 1.0f / dxv;
    float a0 = (-1.0f - sx) * inv, a1 = (256.0f - sx) * inv;
    tlo = fmaxf(tlo, fminf(a0, a1));
    thi = fminf(thi, fmaxf(a0, a1));
  } else if (sx <= -1.0f || sx >= 256.0f) {
    thi = -1.0f;
  }
  if (fabsf(dyv) > 1e-6f) {
    float inv = 1.0f / dyv;
    float a0 = (-1.0f - sy) * inv, a1 = (256.0f - sy) * inv;
    tlo = fmaxf(tlo, fminf(a0, a1));
    thi = fminf(thi, fmaxf(a0, a1));
  } else if (sy <= -1.0f || sy >= 256.0f) {
    thi = -1.0f;
  }
  int imin = (int)ceilf(tlo * 512.0f - 0.5f) - 1;
  imin = imin < 0 ? 0 : imin;
  int imax = (int)floorf(thi * 512.0f - 0.5f) + 1;
  imax = imax > 511 ? 511 : imax;

  float acc = 0.0f;
  for (int i = imin + chunk; i <= imax; i += 8) {
    float t = ((float)i + 0.5f) * (1.0f / 512.0f);
    float cx = fmaf(t, dxv, sx);
    float cy = fmaf(t, dyv, sy);
    cx = fminf(fmaxf(cx, -1.0f), 256.0f);
    cy = fminf(fmaxf(cy, -1.0f), 256.0f);
    float xf = floorf(cx), yf = floorf(cy);
    float fx = cx - xf, fy = cy - yf;
    int ix = (int)xf + 1;
    int iy = (int)yf + 1;
    float4 q = quadP[iy * 258 + ix];
    float gx = 1.0f - fx, gy = 1.0f - fy;
    acc += gy * (gx * q.x + fx * q.y) + fy * (gx * q.z + fx * q.w);
  }
  part[chunk][cell] = acc;
  __syncthreads();
  if (tid < 32) {
    float r = 0.0f;
    #pragma unroll
    for (int q = 0; q < 8; ++q) r += part[q][tid];
    sino[a * 1024 + ((blockIdx.x & 31) << 5) + tid] = r * (L * (1.0f / 512.0f));
  }
}

// ---------------------------------------------------------------------------
// filt64 (R10-verified): one block per angle owns the full 1024-k row;
// diff = filtered - sinogram written directly. No atomics, no init pass.
// ---------------------------------------------------------------------------
__global__ __launch_bounds__(256) void filt64(
    const float* __restrict__ sino_pred, const float* __restrict__ h,
    const float* __restrict__ sino_in, float* __restrict__ diff) {
  __shared__ __align__(16) float srow[1024];
  __shared__ __align__(16) float hext[4104];
  const int a = blockIdx.x;
  const int tid = threadIdx.x;
  for (int n = tid; n < 1024; n += 256) srow[n] = sino_pred[a * 1024 + n];
  for (int n = tid; n < 4104; n += 256) hext[n] = h[(n - 2051) & 2047];
  __syncthreads();
  const int dd0 = tid * 4;
  float acc0 = 0.f, acc1 = 0.f, acc2 = 0.f, acc3 = 0.f;
  #pragma unroll 4
  for (int kk = 0; kk < 1024; kk += 4) {
    float4 sv = *reinterpret_cast<const float4*>(&srow[kk]);
    int nb = dd0 + 2048 - kk;            // in [1028, 3068]
    float4 hA = *reinterpret_cast<const float4*>(&hext[nb]);
    float4 hB = *reinterpret_cast<const float4*>(&hext[nb + 4]);
    acc0 = fmaf(sv.x, hA.w, acc0); acc0 = fmaf(sv.y, hA.z, acc0);
    acc0 = fmaf(sv.z, hA.y, acc0); acc0 = fmaf(sv.w, hA.x, acc0);
    acc1 = fmaf(sv.x, hB.x, acc1); acc1 = fmaf(sv.y, hA.w, acc1);
    acc1 = fmaf(sv.z, hA.z, acc1); acc1 = fmaf(sv.w, hA.y, acc1);
    acc2 = fmaf(sv.x, hB.y, acc2); acc2 = fmaf(sv.y, hB.x, acc2);
    acc2 = fmaf(sv.z, hA.w, acc2); acc2 = fmaf(sv.w, hA.z, acc2);
    acc3 = fmaf(sv.x, hB.z, acc3); acc3 = fmaf(sv.y, hB.y, acc3);
    acc3 = fmaf(sv.z, hB.x, acc3); acc3 = fmaf(sv.w, hA.w, acc3);
  }
  const float4 sref = *reinterpret_cast<const float4*>(&sino_in[a * 1024 + dd0]);
  float* o = diff + a * 1024 + dd0;
  o[0] = acc0 - sref.x;
  o[1] = acc1 - sref.y;
  o[2] = acc2 - sref.z;
  o[3] = acc3 - sref.w;
}

// ---------------------------------------------------------------------------
// Backprojection (R7-verified): angle-split x4, atomicAdd into x_input (= x).
// ---------------------------------------------------------------------------
__global__ __launch_bounds__(256) void backproj_part(
    const float* __restrict__ diff, const float* __restrict__ theta,
    const float* __restrict__ lam_p, float* __restrict__ x_input) {
  __shared__ float cst[16], snt[16];
  const int tid = threadIdx.x;
  const int tileb = blockIdx.x & 255;
  const int a0 = (blockIdx.x >> 8) << 4;
  if (tid < 16) {
    float th = theta[a0 + tid];
    cst[tid] = cosf(th);
    snt[tid] = sinf(th);
  }
  __syncthreads();
  const int tX = (tileb & 3) << 6;
  const int tY = (tileb >> 2) << 2;
  const int pxi = tX + (tid & 63);
  const int pyi = tY + (tid >> 6);
  const float gx = (float)pxi - 127.5f;
  const float gy = (float)pyi - 127.5f;
  float acc = 0.0f;
  for (int ai = 0; ai < 16; ++ai) {
    float c = cst[ai], s = snt[ai];
    float xr = gx * c + gy * s;
    float yr = gy * c - gx * s;
    float denom = 500.0f - xr;
    float inv = 1.0f / denom;
    float uu = yr * 1000.0f * inv;
    float wgt = 250000.0f * inv * inv;
    float iu = uu * 0.5f + 511.5f;
    float i0f = floorf(iu);
    float fr = iu - i0f;
    int i0 = (int)i0f;
    int c0 = min(max(i0, 0), 1023);
    int c1 = min(max(i0 + 1, 0), 1023);
    float m0 = (i0 >= 0 && i0 < 1024) ? 1.0f : 0.0f;
    float m1 = (i0 + 1 >= 0 && i0 + 1 < 1024) ? 1.0f : 0.0f;
    const float* row = diff + (a0 + ai) * 1024;
    float v0 = row[c0] * m0;
    float v1 = row[c1] * m1;
    acc += (v0 * (1.0f - fr) + v1 * fr) * wgt;
  }
  int p = (pyi << 8) + pxi;
  atomicAdd(x_input + p, -lam_p[0] * 0.04908738521234052f * acc);
}

// ---------------------------------------------------------------------------
// conv12f (R11-verified): conv1f + relu (VALU) + conv2f (MFMA, shared B-frag).
// Output packed bf16 pairs: xfp[c2][p] (16 int planes).
// ---------------------------------------------------------------------------
__global__ __launch_bounds__(256) void conv12f(
    const float* __restrict__ x_input, const float* __restrict__ w1f,
    const int* __restrict__ wf2f, int* __restrict__ xfp) {
  __shared__ float xin[8][68];
  __shared__ int htile[6732];            // 396 px * 17 dw
  const int tid = threadIdx.x;
  const int lane = tid & 63;
  const int wave = tid >> 6;
  const int tX = (blockIdx.x & 3) << 6;
  const int tY = (blockIdx.x >> 2) << 2;

  FragI4 wf[2][9];
  const int4* wfg = (const int4*)wf2f;
  #pragma unroll
  for (int mt = 0; mt < 2; ++mt)
    #pragma unroll
    for (int j = 0; j < 9; ++j) wf[mt][j].i4 = wfg[(j * 2 + mt) * 64 + lane];

  for (int idx = tid; idx < 544; idx += 256) {
    int sy = idx / 68;
    int sx = idx - sy * 68;
    int gy = tY + sy - 2, gx = tX + sx - 2;
    xin[sy][sx] = (gy >= 0 && gy < 256 && gx >= 0 && gx < 256)
                      ? x_input[(gy << 8) + gx] : 0.0f;
  }
  __syncthreads();

  for (int pos = tid; pos < 396; pos += 256) {
    int yy = pos / 66;
    int xx = pos - yy * 66;
    int hy = tY + yy - 1, hx = tX + xx - 1;
    bool hin = (hy >= 0 && hy < 256 && hx >= 0 && hx < 256);
    float v[9];
    #pragma unroll
    for (int dy = 0; dy < 3; ++dy)
      #pragma unroll
      for (int dx = 0; dx < 3; ++dx) v[dy * 3 + dx] = xin[yy + dy][xx + dx];
    #pragma unroll
    for (int c2 = 0; c2 < 16; ++c2) {
      float r0 = 0.0f, r1 = 0.0f;
      #pragma unroll
      for (int j = 0; j < 9; ++j) {
        r0 = fmaf(v[j], w1f[(2 * c2) * 9 + j], r0);
        r1 = fmaf(v[j], w1f[(2 * c2 + 1) * 9 + j], r1);
      }
      r0 = hin ? fmaxf(r0, 0.0f) : 0.0f;
      r1 = hin ? fmaxf(r1, 0.0f) : 0.0f;
      htile[pos * 17 + c2] = pack_rne(r0, r1);
    }
  }
  __syncthreads();

  const int y = wave;
  const int n = lane & 15;
  const int q = lane >> 4;
  for (int xt = 0; xt < 4; ++xt) {
    const int x0 = xt << 4;
    f32x4 acc0 = {0.f, 0.f, 0.f, 0.f};
    f32x4 acc1 = {0.f, 0.f, 0.f, 0.f};
    #pragma unroll
    for (int j = 0; j < 9; ++j) {
      int dy = j / 3, dx = j - dy * 3;
      int pb = (y + dy) * 66 + x0 + dx;
      int base = (pb + n) * 17 + q * 4;
      FragI bf;
      bf.i[0] = htile[base];
      bf.i[1] = htile[base + 1];
      bf.i[2] = htile[base + 2];
      bf.i[3] = htile[base + 3];
      acc0 = __builtin_amdgcn_mfma_f32_16x16x32_bf16(wf[0][j].v, bf.v, acc0, 0, 0, 0);
      acc1 = __builtin_amdgcn_mfma_f32_16x16x32_bf16(wf[1][j].v, bf.v, acc1, 0, 0, 0);
    }
    const int gpos = ((tY + y) << 8) + tX + x0 + n;
    xfp[((q * 2) << 16) + gpos]         = pack_rne(acc0[0], acc0[1]);
    xfp[((q * 2 + 1) << 16) + gpos]     = pack_rne(acc0[2], acc0[3]);
    xfp[((8 + q * 2) << 16) + gpos]     = pack_rne(acc1[0], acc1[1]);
    xfp[((8 + q * 2 + 1) << 16) + gpos] = pack_rne(acc1[2], acc1[3]);
  }
}

// ---------------------------------------------------------------------------
// branch_tail, 32x8 tile (3 blocks/CU): per branch (0: soft(xf), 1: xf):
//   stage 36x12 halo2 (432 px x 16 planes) -> ldsX (stride 17)
//   phase A: D = relu(conv1b) on 34x10 halo1 region (MFMA, shared B-frag)
//            30 strip-units: 10 rows x 3 strips (rx0 in {-1,15,17})
//   phase P: P[pp][j] = sum_ci D[pp][ci]*w2b[ci][j] -- 22 MFMAs
//   epilogue: out[p] = sum_j P[p+off(j)][j]
// LDS: 7344 + 5984 ints = 52.1 KB -> 3 blocks/CU.
// ---------------------------------------------------------------------------
__global__ __launch_bounds__(256) void branch_tail(
    const int* __restrict__ xfp, const int* __restrict__ wf1b,
    const int* __restrict__ wf2b, const float* __restrict__ thr_p,
    const float* __restrict__ x_input, float* __restrict__ out) {
  __shared__ int ldsX[7344];             // 432 px (36x12) * 17 dw
  __shared__ int ldsD[5984];             // 352 px (34x10 +pad) * 17 dw
  float* ldsP = (float*)ldsX;            // aliases ldsX after phase A
  const int tid = threadIdx.x;
  const int lane = tid & 63;
  const int wave = tid >> 6;
  const int branch = blockIdx.x >> 8;
  const int tileb = blockIdx.x & 255;
  const int tX = (tileb & 7) << 5;       // 8 x-tiles of 32
  const int tY = (tileb >> 3) << 3;      // 32 y-tiles of 8
  const float thr = thr_p[0];
  const bool soft = (branch == 0);

  FragI4 wf[2][9];
  const int4* wfg = (const int4*)wf1b;
  #pragma unroll
  for (int mt = 0; mt < 2; ++mt)
    #pragma unroll
    for (int j = 0; j < 9; ++j) wf[mt][j].i4 = wfg[(j * 2 + mt) * 64 + lane];
  FragI4 wb;
  wb.i4 = ((const int4*)wf2b)[lane];

  // staging: 432 px, 2 per thread; coords precomputed once.
  int pp[2], ga[2];
  bool ok[2];
  #pragma unroll
  for (int t = 0; t < 2; ++t) {
    int p = tid + t * 256;
    pp[t] = p;
    int sy = p / 36;
    int sx = p - sy * 36;
    int gy = tY + sy - 2, gx = tX + sx - 2;
    ok[t] = (p < 432) && ((unsigned)gy < 256u) && ((unsigned)gx < 256u);
    ga[t] = (gy << 8) + gx;
  }
  #pragma unroll
  for (int c2 = 0; c2 < 16; ++c2) {
    #pragma unroll
    for (int t = 0; t < 2; ++t) {
      if (pp[t] < 432) {
        int v = ok[t] ? xfp[(c2 << 16) + ga[t]] : 0;
        if (soft) {
          float lo = __uint_as_float(((unsigned)v) << 16);
          float hi = __uint_as_float(((unsigned)v) & 0xFFFF0000u);
          lo = fmaxf(lo - thr, 0.0f) + fminf(lo + thr, 0.0f);
          hi = fmaxf(hi - thr, 0.0f) + fminf(hi + thr, 0.0f);
          v = pack_rne(lo, hi);
        }
        ldsX[pp[t] * 17 + c2] = v;
      }
    }
  }
  __syncthreads();

  // phase A: D = relu(conv1b) over region rx -1..32, ry -1..8.
  const int n = lane & 15;
  const int q = lane >> 4;
  const int rx0tab[3] = {-1, 15, 17};
  for (int t = wave; t < 30; t += 4) {
    int trow = t / 3;                    // 0..9
    int ry = trow - 1;                   // -1..8
    int rx0 = rx0tab[t - trow * 3];
    int rxn = rx0 + n;                   // -1..32
    bool inimg = ((unsigned)(tX + rxn) < 256u) && ((unsigned)(tY + ry) < 256u);
    int wrbase = ((ry + 1) * 34 + rxn + 1) * 17;
    f32x4 acc0 = {0.f, 0.f, 0.f, 0.f};
    f32x4 acc1 = {0.f, 0.f, 0.f, 0.f};
    #pragma unroll
    for (int j = 0; j < 9; ++j) {
      int dy = j / 3, dx = j - dy * 3;
      int pb = (ry + 1 + dy) * 36 + rx0 + 1 + dx;
      int base = (pb + n) * 17 + q * 4;
      FragI bf;
      bf.i[0] = ldsX[base];
      bf.i[1] = ldsX[base + 1];
      bf.i[2] = ldsX[base + 2];
      bf.i[3] = ldsX[base + 3];
      acc0 = __builtin_amdgcn_mfma_f32_16x16x32_bf16(wf[0][j].v, bf.v, acc0, 0, 0, 0);
      acc1 = __builtin_amdgcn_mfma_f32_16x16x32_bf16(wf[1][j].v, bf.v, acc1, 0, 0, 0);
    }
    float a00 = inimg ? fmaxf(acc0[0], 0.0f) : 0.0f;
    float a01 = inimg ? fmaxf(acc0[1], 0.0f) : 0.0f;
    float a02 = inimg ? fmaxf(acc0[2], 0.0f) : 0.0f;
    float a03 = inimg ? fmaxf(acc0[3], 0.0f) : 0.0f;
    float a10 = inimg ? fmaxf(acc1[0], 0.0f) : 0.0f;
    float a11 = inimg ? fmaxf(acc1[1], 0.0f) : 0.0f;
    float a12 = inimg ? fmaxf(acc1[2], 0.0f) : 0.0f;
    float a13 = inimg ? fmaxf(acc1[3], 0.0f) : 0.0f;
    ldsD[wrbase + q * 2]         = pack_rne(a00, a01);
    ldsD[wrbase + q * 2 + 1]     = pack_rne(a02, a03);
    ldsD[wrbase + 8 + q * 2]     = pack_rne(a10, a11);
    ldsD[wrbase + 8 + q * 2 + 1] = pack_rne(a12, a13);
  }
  __syncthreads();

  // phase P: 22 tiles of 16 px; one MFMA each (A=D, B=wf2b).
  // Rows 340..351 of ldsD are unwritten garbage -> garbage P rows, never read.
  for (int t = wave; t < 22; t += 4) {
    int pbase = t << 4;
    int abase = (pbase + n) * 17 + q * 4;
    FragI af;
    af.i[0] = ldsD[abase];
    af.i[1] = ldsD[abase + 1];
    af.i[2] = ldsD[abase + 2];
    af.i[3] = ldsD[abase + 3];
    f32x4 acc = {0.f, 0.f, 0.f, 0.f};
    acc = __builtin_amdgcn_mfma_f32_16x16x32_bf16(af.v, wb.v, acc, 0, 0, 0);
    #pragma unroll
    for (int r = 0; r < 4; ++r)
      ldsP[(pbase + q * 4 + r) * 17 + n] = acc[r];
  }
  __syncthreads();

  // epilogue: out[p] = sum_j P[p+off(j)][j]
  const int px = tid & 31, py = tid >> 5;
  float acc = 0.0f;
  #pragma unroll
  for (int j = 0; j < 9; ++j) {
    int dy = j / 3, dx = j - dy * 3;
    int rp = (py + dy) * 34 + px + dx;
    acc += ldsP[rp * 17 + j];
  }
  const int p = ((tY + py) << 8) + tX + px;
  if (branch == 0) out[p] = acc;
  else out[65536 + p] = acc - x_input[p];
}

extern "C" void kernel_launch(void* const* d_in, const int* in_sizes, int n_in,
                              void* d_out, int out_size, void* d_ws, size_t ws_size,
                              hipStream_t stream) {
  const float* x       = (const float*)d_in[0];
  const float* theta   = (const float*)d_in[1];
  const float* sino_in = (const float*)d_in[2];
  const float* lam     = (const float*)d_in[3];
  const float* thr     = (const float*)d_in[4];
  const float* w_c1f   = (const float*)d_in[5];
  const float* w_c2f   = (const float*)d_in[6];
  const float* w_c1b   = (const float*)d_in[7];
  const float* w_c2b   = (const float*)d_in[8];
  float* out = (float*)d_out;
  float* ws  = (float*)d_ws;

  float* h         = ws + H_OFF;
  float* sino_pred = ws + SINO_OFF;
  float* diff      = ws + DIFF_OFF;
  float* x_input   = ws + XIN_OFF;
  int*   wf2f      = (int*)(ws + WF2F_OFF);
  int*   wf1b      = (int*)(ws + WF1B_OFF);
  int*   wf2b      = (int*)(ws + WF2B_OFF);
  float4* quadP    = (float4*)(ws + BUFA_OFF);   // dead once fwdproj completes
  int*   xfp       = (int*)(ws + BUFB_OFF);      // x_forward, packed bf16 pairs

  setup_kernel<<<618, 256, 0, stream>>>(w_c2f, w_c1b, w_c2b, x, h, wf2f,
                                        wf1b, wf2b, quadP, x_input);
  fwdproj<<<2048, 256, 0, stream>>>(quadP, theta, sino_pred);
  filt64<<<64, 256, 0, stream>>>(sino_pred, h, sino_in, diff);
  backproj_part<<<1024, 256, 0, stream>>>(diff, theta, lam, x_input);
  conv12f<<<256, 256, 0, stream>>>(x_input, w_c1f, wf2f, xfp);
  branch_tail<<<512, 256, 0, stream>>>(xfp, wf1b, wf2b, thr, x_input, out);
}

// Round 15
// 131.759 us; speedup vs baseline: 1.1817x; 1.1817x over previous
//
#include <hip/hip_runtime.h>

#define DEV_INLINE __device__ __forceinline__

// Problem constants
#define PI_F 3.14159265358979323846f

// ws layout (float offsets)
#define H_OFF     0          // 2048
#define SINO_OFF  2048       // 65536
#define DIFF_OFF  67584      // 65536
#define XIN_OFF   133120     // 65536
#define WF2F_OFF  198656     // 4608 ints (18 groups x 64 lanes x int4)
#define WF1B_OFF  207872     // 4608 ints
#define WF2B_OFF  212480     // 256 ints (B-frag of conv2_backward weights)
#define BUFA_OFF  217088     // quadP lives here (258*258 float4)
#define BUFB_OFF  2314240    // xfp: x_forward PIXEL-MAJOR: [gpos*16 + c2]

typedef short bf16x8 __attribute__((ext_vector_type(8)));
typedef float f32x4 __attribute__((ext_vector_type(4)));

union FragI4 { int4 i4; bf16x8 v; };
union FragI  { int i[4]; bf16x8 v; };
union I4U    { int4 i4; int i[4]; };

DEV_INLINE unsigned rne1(float a) {
  unsigned u = __float_as_uint(a);
  return (u + 0x7FFFu + ((u >> 16) & 1u)) >> 16;
}
DEV_INLINE int pack_rne(float a, float b) {
  return (int)(rne1(a) | (rne1(b) << 16));
}

// ---------------------------------------------------------------------------
// Setup (R13-verified): h | diff=-sino | wf2f | wf1b | quadP | x_input=x | wf2b
// blocks: 0..63 h | 64..319 diff | 320..337 wf2f | 338..355 wf1b |
//         356..616 quadP | 617..872 x_input=x | 873 wf2b
// ---------------------------------------------------------------------------
__global__ __launch_bounds__(256) void setup_kernel(
    const float* __restrict__ sino_in, const float* __restrict__ w2f,
    const float* __restrict__ w1b, const float* __restrict__ w2b,
    const float* __restrict__ img,
    float* __restrict__ h, float* __restrict__ diff,
    int* __restrict__ wf2f, int* __restrict__ wf1b, int* __restrict__ wf2b,
    float4* __restrict__ quadP, float* __restrict__ x_input) {
  const int b = blockIdx.x;
  const int tid = threadIdx.x;
  if (b < 64) {
    __shared__ float hp[8][32];
    const int cell = tid & 31;
    const int kq = tid >> 5;
    const int n = b * 32 + cell;
    float ssum = 0.0f;
    const float ang_scale = PI_F / 1024.0f;
    for (int k = kq * 128; k < kq * 128 + 128; ++k) {
      int m = (k * n) & 2047;             // exact angle reduction mod 2*pi
      ssum += (float)k * __cosf((float)m * ang_scale);
    }
    hp[kq][cell] = ssum;
    __syncthreads();
    if (tid < 32) {
      float S = 0.0f;
      #pragma unroll
      for (int q = 0; q < 8; ++q) S += hp[q][tid];
      int nn = b * 32 + tid;
      float sgn = (nn & 1) ? -1.0f : 1.0f;
      h[nn] = (S * (1.0f / 512.0f) + sgn) * (1.0f / 2048.0f);
    }
  } else if (b < 320) {
    int idx = (b - 64) * 256 + tid;       // < 65536
    diff[idx] = -sino_in[idx];
  } else if (b < 356) {
    const bool second = (b >= 338);
    int idx = (b - (second ? 338 : 320)) * 256 + tid;   // < 4608
    int d = idx & 3;
    int L = (idx >> 2) & 63;
    int jm = idx >> 8;                    // 0..17
    int j = jm >> 1, mt = jm & 1;
    int co = mt * 16 + (L & 15);
    int ci0 = (L >> 4) * 8 + 2 * d;
    const float* w = second ? w1b : w2f;
    int v = pack_rne(w[co * 288 + ci0 * 9 + j], w[co * 288 + (ci0 + 1) * 9 + j]);
    (second ? wf1b : wf2f)[idx] = v;
  } else if (b < 617) {
    int idx = (b - 356) * 256 + tid;
    if (idx < 258 * 258) {
      int y = idx / 258;
      int x = idx - y * 258;
      float4 v;
      int ay = y - 1, bx = x - 1;          // img coords for P(y,x)
      bool y0ok = (ay >= 0 && ay < 256);
      bool y1ok = (ay + 1 >= 0 && ay + 1 < 256);
      bool x0ok = (bx >= 0 && bx < 256);
      bool x1ok = (bx + 1 >= 0 && bx + 1 < 256);
      v.x = (y0ok && x0ok) ? img[(ay << 8) + bx] : 0.0f;
      v.y = (y0ok && x1ok) ? img[(ay << 8) + bx + 1] : 0.0f;
      v.z = (y1ok && x0ok) ? img[((ay + 1) << 8) + bx] : 0.0f;
      v.w = (y1ok && x1ok) ? img[((ay + 1) << 8) + bx + 1] : 0.0f;
      quadP[idx] = v;
    }
  } else if (b < 873) {
    int idx = (b - 617) * 256 + tid;      // < 65536
    x_input[idx] = img[idx];
  } else {
    // wf2b B-frag: 256 ints; n>=9 columns zero.
    int d = tid & 3;
    int L = tid >> 2;
    int n = L & 15;
    int k0 = (L >> 4) * 8 + 2 * d;
    float lo = (n < 9) ? w2b[k0 * 9 + n] : 0.0f;
    float hi = (n < 9) ? w2b[(k0 + 1) * 9 + n] : 0.0f;
    wf2b[tid] = pack_rne(lo, hi);
  }
}

// ---------------------------------------------------------------------------
// Fan-beam forward projection (verified, unchanged).
// ---------------------------------------------------------------------------
__global__ __launch_bounds__(256) void fwdproj(
    const float4* __restrict__ quadP, const float* __restrict__ theta,
    float* __restrict__ sino) {
  __shared__ float part[8][32];
  __shared__ float cs[2];
  const int tid = threadIdx.x;
  const int a = blockIdx.x >> 5;
  const int cell = tid & 31;
  const int chunk = tid >> 5;
  const int d = ((blockIdx.x & 31) << 5) + cell;
  if (tid == 0) {
    float th = theta[a];
    cs[0] = cosf(th);
    cs[1] = sinf(th);
  }
  __syncthreads();
  const float c = cs[0], s = cs[1];
  const float u = ((float)d - 511.5f) * 2.0f;
  const float dxv = -1000.0f * c - u * s;
  const float dyv = -1000.0f * s + u * c;
  const float L = sqrtf(1.0e6f + u * u);
  const float sx = fmaf(500.0f, c, 127.5f);
  const float sy = fmaf(500.0f, s, 127.5f);

  float tlo = 0.0f, thi = 1.0f;
  if (fabsf(dxv) > 1e-6f) {
    float inv = 1.0f / dxv;
    float a0 = (-1.0f - sx) * inv, a1 = (256.0f - sx) * inv;
    tlo = fmaxf(tlo, fminf(a0, a1));
    thi = fminf(thi, fmaxf(a0, a1));
  } else if (sx <= -1.0f || sx >= 256.0f) {
    thi = -1.0f;
  }
  if (fabsf(dyv) > 1e-6f) {
    float inv = 1.0f / dyv;
    float a0 = (-1.0f - sy) * inv, a1 = (256.0f - sy) * inv;
    tlo = fmaxf(tlo, fminf(a0, a1));
    thi = fminf(thi, fmaxf(a0, a1));
  } else if (sy <= -1.0f || sy >= 256.0f) {
    thi = -1.0f;
  }
  int imin = (int)ceilf(tlo * 512.0f - 0.5f) - 1;
  imin = imin < 0 ? 0 : imin;
  int imax = (int)floorf(thi * 512.0f - 0.5f) + 1;
  imax = imax > 511 ? 511 : imax;

  float acc = 0.0f;
  for (int i = imin + chunk; i <= imax; i += 8) {
    float t = ((float)i + 0.5f) * (1.0f / 512.0f);
    float cx = fmaf(t, dxv, sx);
    float cy = fmaf(t, dyv, sy);
    cx = fminf(fmaxf(cx, -1.0f), 256.0f);
    cy = fminf(fmaxf(cy, -1.0f), 256.0f);
    float xf = floorf(cx), yf = floorf(cy);
    float fx = cx - xf, fy = cy - yf;
    int ix = (int)xf + 1;
    int iy = (int)yf + 1;
    float4 q = quadP[iy * 258 + ix];
    float gx = 1.0f - fx, gy = 1.0f - fy;
    acc += gy * (gx * q.x + fx * q.y) + fy * (gx * q.z + fx * q.w);
  }
  part[chunk][cell] = acc;
  __syncthreads();
  if (tid < 32) {
    float r = 0.0f;
    #pragma unroll
    for (int q = 0; q < 8; ++q) r += part[q][tid];
    sino[a * 1024 + ((blockIdx.x & 31) << 5) + tid] = r * (L * (1.0f / 512.0f));
  }
}

// ---------------------------------------------------------------------------
// Ramp filter (R7-verified): k-split x4, atomicAdd into diff (= -sinogram).
// ---------------------------------------------------------------------------
__global__ __launch_bounds__(256) void filt(
    const float* __restrict__ sino_pred, const float* __restrict__ h,
    float* __restrict__ diff) {
  __shared__ __align__(16) float srow[256];
  __shared__ __align__(16) float hext[4104];
  const int a = blockIdx.x >> 2;
  const int q = blockIdx.x & 3;
  const int tid = threadIdx.x;
  const int k0base = q * 256;
  srow[tid] = sino_pred[a * 1024 + k0base + tid];
  for (int n = tid; n < 4104; n += 256) hext[n] = h[(n - 2051) & 2047];
  __syncthreads();
  const int dd0 = tid * 4;
  float acc0 = 0.f, acc1 = 0.f, acc2 = 0.f, acc3 = 0.f;
  #pragma unroll 4
  for (int kk = 0; kk < 256; kk += 4) {
    float4 sv = *reinterpret_cast<const float4*>(&srow[kk]);
    int nb = dd0 + 2048 - k0base - kk;
    float4 hA = *reinterpret_cast<const float4*>(&hext[nb]);
    float4 hB = *reinterpret_cast<const float4*>(&hext[nb + 4]);
    acc0 = fmaf(sv.x, hA.w, acc0); acc0 = fmaf(sv.y, hA.z, acc0);
    acc0 = fmaf(sv.z, hA.y, acc0); acc0 = fmaf(sv.w, hA.x, acc0);
    acc1 = fmaf(sv.x, hB.x, acc1); acc1 = fmaf(sv.y, hA.w, acc1);
    acc1 = fmaf(sv.z, hA.z, acc1); acc1 = fmaf(sv.w, hA.y, acc1);
    acc2 = fmaf(sv.x, hB.y, acc2); acc2 = fmaf(sv.y, hB.x, acc2);
    acc2 = fmaf(sv.z, hA.w, acc2); acc2 = fmaf(sv.w, hA.z, acc2);
    acc3 = fmaf(sv.x, hB.z, acc3); acc3 = fmaf(sv.y, hB.y, acc3);
    acc3 = fmaf(sv.z, hB.x, acc3); acc3 = fmaf(sv.w, hA.w, acc3);
  }
  float* o = diff + a * 1024 + dd0;
  atomicAdd(o + 0, acc0);
  atomicAdd(o + 1, acc1);
  atomicAdd(o + 2, acc2);
  atomicAdd(o + 3, acc3);
}

// ---------------------------------------------------------------------------
// Backprojection (R7-verified): angle-split x4, atomicAdd into x_input (= x).
// ---------------------------------------------------------------------------
__global__ __launch_bounds__(256) void backproj_part(
    const float* __restrict__ diff, const float* __restrict__ theta,
    const float* __restrict__ lam_p, float* __restrict__ x_input) {
  __shared__ float cst[16], snt[16];
  const int tid = threadIdx.x;
  const int tileb = blockIdx.x & 255;
  const int a0 = (blockIdx.x >> 8) << 4;
  if (tid < 16) {
    float th = theta[a0 + tid];
    cst[tid] = cosf(th);
    snt[tid] = sinf(th);
  }
  __syncthreads();
  const int tX = (tileb & 3) << 6;
  const int tY = (tileb >> 2) << 2;
  const int pxi = tX + (tid & 63);
  const int pyi = tY + (tid >> 6);
  const float gx = (float)pxi - 127.5f;
  const float gy = (float)pyi - 127.5f;
  float acc = 0.0f;
  for (int ai = 0; ai < 16; ++ai) {
    float c = cst[ai], s = snt[ai];
    float xr = gx * c + gy * s;
    float yr = gy * c - gx * s;
    float denom = 500.0f - xr;
    float inv = 1.0f / denom;
    float uu = yr * 1000.0f * inv;
    float wgt = 250000.0f * inv * inv;
    float iu = uu * 0.5f + 511.5f;
    float i0f = floorf(iu);
    float fr = iu - i0f;
    int i0 = (int)i0f;
    int c0 = min(max(i0, 0), 1023);
    int c1 = min(max(i0 + 1, 0), 1023);
    float m0 = (i0 >= 0 && i0 < 1024) ? 1.0f : 0.0f;
    float m1 = (i0 + 1 >= 0 && i0 + 1 < 1024) ? 1.0f : 0.0f;
    const float* row = diff + (a0 + ai) * 1024;
    float v0 = row[c0] * m0;
    float v1 = row[c1] * m1;
    acc += (v0 * (1.0f - fr) + v1 * fr) * wgt;
  }
  int p = (pyi << 8) + pxi;
  atomicAdd(x_input + p, -lam_p[0] * 0.04908738521234052f * acc);
}

// ---------------------------------------------------------------------------
// conv12f: conv1f + relu (VALU) + conv2f (MFMA, shared B-frag).
// Output PIXEL-MAJOR packed bf16 pairs: xfp[gpos*16 + c2] (int2 stores).
// ---------------------------------------------------------------------------
__global__ __launch_bounds__(256) void conv12f(
    const float* __restrict__ x_input, const float* __restrict__ w1f,
    const int* __restrict__ wf2f, int* __restrict__ xfp) {
  __shared__ float xin[8][68];
  __shared__ int htile[6732];            // 396 px * 17 dw
  const int tid = threadIdx.x;
  const int lane = tid & 63;
  const int wave = tid >> 6;
  const int tX = (blockIdx.x & 3) << 6;
  const int tY = (blockIdx.x >> 2) << 2;

  FragI4 wf[2][9];
  const int4* wfg = (const int4*)wf2f;
  #pragma unroll
  for (int mt = 0; mt < 2; ++mt)
    #pragma unroll
    for (int j = 0; j < 9; ++j) wf[mt][j].i4 = wfg[(j * 2 + mt) * 64 + lane];

  for (int idx = tid; idx < 544; idx += 256) {
    int sy = idx / 68;
    int sx = idx - sy * 68;
    int gy = tY + sy - 2, gx = tX + sx - 2;
    xin[sy][sx] = (gy >= 0 && gy < 256 && gx >= 0 && gx < 256)
                      ? x_input[(gy << 8) + gx] : 0.0f;
  }
  __syncthreads();

  for (int pos = tid; pos < 396; pos += 256) {
    int yy = pos / 66;
    int xx = pos - yy * 66;
    int hy = tY + yy - 1, hx = tX + xx - 1;
    bool hin = (hy >= 0 && hy < 256 && hx >= 0 && hx < 256);
    float v[9];
    #pragma unroll
    for (int dy = 0; dy < 3; ++dy)
      #pragma unroll
      for (int dx = 0; dx < 3; ++dx) v[dy * 3 + dx] = xin[yy + dy][xx + dx];
    #pragma unroll
    for (int c2 = 0; c2 < 16; ++c2) {
      float r0 = 0.0f, r1 = 0.0f;
      #pragma unroll
      for (int j = 0; j < 9; ++j) {
        r0 = fmaf(v[j], w1f[(2 * c2) * 9 + j], r0);
        r1 = fmaf(v[j], w1f[(2 * c2 + 1) * 9 + j], r1);
      }
      r0 = hin ? fmaxf(r0, 0.0f) : 0.0f;
      r1 = hin ? fmaxf(r1, 0.0f) : 0.0f;
      htile[pos * 17 + c2] = pack_rne(r0, r1);
    }
  }
  __syncthreads();

  const int y = wave;
  const int n = lane & 15;
  const int q = lane >> 4;
  for (int xt = 0; xt < 4; ++xt) {
    const int x0 = xt << 4;
    f32x4 acc0 = {0.f, 0.f, 0.f, 0.f};
    f32x4 acc1 = {0.f, 0.f, 0.f, 0.f};
    #pragma unroll
    for (int j = 0; j < 9; ++j) {
      int dy = j / 3, dx = j - dy * 3;
      int pb = (y + dy) * 66 + x0 + dx;
      int base = (pb + n) * 17 + q * 4;
      FragI bf;
      bf.i[0] = htile[base];
      bf.i[1] = htile[base + 1];
      bf.i[2] = htile[base + 2];
      bf.i[3] = htile[base + 3];
      acc0 = __builtin_amdgcn_mfma_f32_16x16x32_bf16(wf[0][j].v, bf.v, acc0, 0, 0, 0);
      acc1 = __builtin_amdgcn_mfma_f32_16x16x32_bf16(wf[1][j].v, bf.v, acc1, 0, 0, 0);
    }
    const int gpos = ((tY + y) << 8) + tX + x0 + n;
    int2* xp = (int2*)(xfp + (gpos << 4));
    xp[q]     = make_int2(pack_rne(acc0[0], acc0[1]), pack_rne(acc0[2], acc0[3]));
    xp[4 + q] = make_int2(pack_rne(acc1[0], acc1[1]), pack_rne(acc1[2], acc1[3]));
  }
}

// ---------------------------------------------------------------------------
// branch_tail (R13-verified structure): per branch (0: soft(xf), 1: xf):
//   staging now PIXEL-MAJOR: 4x global_load_dwordx4 per pixel (was 16 scattered
//   dword loads) -- full 64B cache-line utilization.
//   phase A: D = relu(conv1b) on 66x6 halo (MFMA, shared B-frag) -> ldsD
//   phase P: P[pp][j] via one MFMA per 16 px (A=D, B=wf2b)
//   epilogue: out[p] = sum_j P[p+off(j)][j]
// ---------------------------------------------------------------------------
__global__ __launch_bounds__(256) void branch_tail(
    const int* __restrict__ xfp, const int* __restrict__ wf1b,
    const int* __restrict__ wf2b, const float* __restrict__ thr_p,
    const float* __restrict__ x_input, float* __restrict__ out) {
  __shared__ int ldsX[9248];             // 544 px (68x8 halo2) * 17 dw
  __shared__ int ldsD[6800];             // 400 px (66x6 +pad) * 17 dw
  float* ldsP = (float*)ldsX;            // aliases ldsX after phase A
  const int tid = threadIdx.x;
  const int lane = tid & 63;
  const int wave = tid >> 6;
  const int branch = blockIdx.x >> 8;
  const int tileb = blockIdx.x & 255;
  const int tX = (tileb & 3) << 6;
  const int tY = (tileb >> 2) << 2;
  const float thr = thr_p[0];
  const bool soft = (branch == 0);

  FragI4 wf[2][9];
  const int4* wfg = (const int4*)wf1b;
  #pragma unroll
  for (int mt = 0; mt < 2; ++mt)
    #pragma unroll
    for (int j = 0; j < 9; ++j) wf[mt][j].i4 = wfg[(j * 2 + mt) * 64 + lane];
  FragI4 wb;
  wb.i4 = ((const int4*)wf2b)[lane];

  // staging: <=3 px/thread, 4 int4 loads each (pixel-major xfp).
  #pragma unroll
  for (int t = 0; t < 3; ++t) {
    int p = tid + t * 256;
    if (p < 544) {
      int sy = p / 68;
      int sx = p - sy * 68;
      int gy = tY + sy - 2, gx = tX + sx - 2;
      bool ok = ((unsigned)gy < 256u) && ((unsigned)gx < 256u);
      I4U w0, w1, w2, w3;
      if (ok) {
        const int4* src = (const int4*)(xfp + (((gy << 8) + gx) << 4));
        w0.i4 = src[0]; w1.i4 = src[1]; w2.i4 = src[2]; w3.i4 = src[3];
      } else {
        w0.i4 = w1.i4 = w2.i4 = w3.i4 = make_int4(0, 0, 0, 0);
      }
      int base = p * 17;
      #pragma unroll
      for (int k = 0; k < 4; ++k) {
        int vals[4] = {w0.i[k], w1.i[k], w2.i[k], w3.i[k]};
        // order: group g holds c2 = g*4 + k? No: src[g].i[k] is c2 = g*4+k.
        (void)vals;
      }
      // write c2 = g*4 + k from group g, element k
      I4U* grp[4] = {&w0, &w1, &w2, &w3};
      #pragma unroll
      for (int g = 0; g < 4; ++g) {
        #pragma unroll
        for (int k = 0; k < 4; ++k) {
          int v = grp[g]->i[k];
          if (soft) {
            float lo = __uint_as_float(((unsigned)v) << 16);
            float hi = __uint_as_float(((unsigned)v) & 0xFFFF0000u);
            lo = fmaxf(lo - thr, 0.0f) + fminf(lo + thr, 0.0f);
            hi = fmaxf(hi - thr, 0.0f) + fminf(hi + thr, 0.0f);
            v = pack_rne(lo, hi);
          }
          ldsX[base + g * 4 + k] = v;
        }
      }
    }
  }
  __syncthreads();

  // phase A: D = relu(conv1b) over region rx -1..64, ry -1..4 (16px units).
  const int n = lane & 15;
  const int q = lane >> 4;
  const int rxtab[5] = {-1, 15, 31, 47, 49};
  for (int t = wave; t < 30; t += 4) {
    int trow = t / 5;
    int ry = trow - 1;
    int rx0 = rxtab[t - trow * 5];
    int rxn = rx0 + n;
    bool inimg = ((unsigned)(tX + rxn) < 256u) && ((unsigned)(tY + ry) < 256u);
    int wrbase = ((ry + 1) * 66 + rxn + 1) * 17;
    f32x4 acc0 = {0.f, 0.f, 0.f, 0.f};
    f32x4 acc1 = {0.f, 0.f, 0.f, 0.f};
    #pragma unroll
    for (int j = 0; j < 9; ++j) {
      int dy = j / 3, dx = j - dy * 3;
      int pb = (ry + 1 + dy) * 68 + rx0 + 1 + dx;
      int base = (pb + n) * 17 + q * 4;
      FragI bf;
      bf.i[0] = ldsX[base];
      bf.i[1] = ldsX[base + 1];
      bf.i[2] = ldsX[base + 2];
      bf.i[3] = ldsX[base + 3];
      acc0 = __builtin_amdgcn_mfma_f32_16x16x32_bf16(wf[0][j].v, bf.v, acc0, 0, 0, 0);
      acc1 = __builtin_amdgcn_mfma_f32_16x16x32_bf16(wf[1][j].v, bf.v, acc1, 0, 0, 0);
    }
    float a00 = inimg ? fmaxf(acc0[0], 0.0f) : 0.0f;
    float a01 = inimg ? fmaxf(acc0[1], 0.0f) : 0.0f;
    float a02 = inimg ? fmaxf(acc0[2], 0.0f) : 0.0f;
    float a03 = inimg ? fmaxf(acc0[3], 0.0f) : 0.0f;
    float a10 = inimg ? fmaxf(acc1[0], 0.0f) : 0.0f;
    float a11 = inimg ? fmaxf(acc1[1], 0.0f) : 0.0f;
    float a12 = inimg ? fmaxf(acc1[2], 0.0f) : 0.0f;
    float a13 = inimg ? fmaxf(acc1[3], 0.0f) : 0.0f;
    ldsD[wrbase + q * 2]         = pack_rne(a00, a01);
    ldsD[wrbase + q * 2 + 1]     = pack_rne(a02, a03);
    ldsD[wrbase + 8 + q * 2]     = pack_rne(a10, a11);
    ldsD[wrbase + 8 + q * 2 + 1] = pack_rne(a12, a13);
  }
  __syncthreads();

  // phase P: 25 M-tiles of 16 px; one MFMA each (A=D, B=wf2b).
  for (int t = wave; t < 25; t += 4) {
    int pbase = t << 4;
    int abase = (pbase + n) * 17 + q * 4;
    FragI af;
    af.i[0] = ldsD[abase];
    af.i[1] = ldsD[abase + 1];
    af.i[2] = ldsD[abase + 2];
    af.i[3] = ldsD[abase + 3];
    f32x4 acc = {0.f, 0.f, 0.f, 0.f};
    acc = __builtin_amdgcn_mfma_f32_16x16x32_bf16(af.v, wb.v, acc, 0, 0, 0);
    #pragma unroll
    for (int r = 0; r < 4; ++r)
      ldsP[(pbase + q * 4 + r) * 17 + n] = acc[r];
  }
  __syncthreads();

  // epilogue: out[p] = sum_j P[p+off(j)][j]
  const int px = tid & 63, py = tid >> 6;
  float acc = 0.0f;
  #pragma unroll
  for (int j = 0; j < 9; ++j) {
    int dy = j / 3, dx = j - dy * 3;
    int rp = (py + dy) * 66 + px + dx;
    acc += ldsP[rp * 17 + j];
  }
  const int p = ((tY + py) << 8) + tX + px;
  if (branch == 0) out[p] = acc;
  else out[65536 + p] = acc - x_input[p];
}

extern "C" void kernel_launch(void* const* d_in, const int* in_sizes, int n_in,
                              void* d_out, int out_size, void* d_ws, size_t ws_size,
                              hipStream_t stream) {
  const float* x       = (const float*)d_in[0];
  const float* theta   = (const float*)d_in[1];
  const float* sino_in = (const float*)d_in[2];
  const float* lam     = (const float*)d_in[3];
  const float* thr     = (const float*)d_in[4];
  const float* w_c1f   = (const float*)d_in[5];
  const float* w_c2f   = (const float*)d_in[6];
  const float* w_c1b   = (const float*)d_in[7];
  const float* w_c2b   = (const float*)d_in[8];
  float* out = (float*)d_out;
  float* ws  = (float*)d_ws;

  float* h         = ws + H_OFF;
  float* sino_pred = ws + SINO_OFF;
  float* diff      = ws + DIFF_OFF;
  float* x_input   = ws + XIN_OFF;
  int*   wf2f      = (int*)(ws + WF2F_OFF);
  int*   wf1b      = (int*)(ws + WF1B_OFF);
  int*   wf2b      = (int*)(ws + WF2B_OFF);
  float4* quadP    = (float4*)(ws + BUFA_OFF);   // dead once fwdproj completes
  int*   xfp       = (int*)(ws + BUFB_OFF);      // x_forward, pixel-major bf16

  setup_kernel<<<874, 256, 0, stream>>>(sino_in, w_c2f, w_c1b, w_c2b, x, h,
                                        diff, wf2f, wf1b, wf2b, quadP, x_input);
  fwdproj<<<2048, 256, 0, stream>>>(quadP, theta, sino_pred);
  filt<<<256, 256, 0, stream>>>(sino_pred, h, diff);
  backproj_part<<<1024, 256, 0, stream>>>(diff, theta, lam, x_input);
  conv12f<<<256, 256, 0, stream>>>(x_input, w_c1f, wf2f, xfp);
  branch_tail<<<512, 256, 0, stream>>>(xfp, wf1b, wf2b, thr, x_input, out);
}